// Round 1
// baseline (971.012 us; speedup 1.0000x reference)
//
#include <hip/hip_runtime.h>
#include <math.h>

#define N2C 16000
#define N1C 4000
#define N0C 1000
#define DEG 32
#define NHEAD 4
#define ALPHA 0.2f
#define LDP 264     // padded LDS row pitch (ushorts): 264*2=528 B, 16B-aligned, 2-way banks
#define NBLK 768    // 3 blocks/CU x 256 CUs — co-residency guaranteed by launch_bounds(256,3)

typedef __attribute__((ext_vector_type(8))) short bf16x8;
typedef __attribute__((ext_vector_type(4))) float f32x4;

__device__ __forceinline__ ushort f2bf(float f) {
    unsigned u = __float_as_uint(f);
    unsigned r = (u + 0x7fffu + ((u >> 16) & 1u)) >> 16;   // RTNE
    return (ushort)r;
}
__device__ __forceinline__ float bf2f(ushort h) {
    return __uint_as_float(((unsigned)h) << 16);
}

// ---- grid-wide sense-reversal barrier (agent-scope atomics: coherent across XCD L2s) ----
__device__ __forceinline__ void grid_sync(int* bar) {
    __syncthreads();
    if (threadIdx.x == 0) {
        int gen = __hip_atomic_load(bar + 1, __ATOMIC_RELAXED, __HIP_MEMORY_SCOPE_AGENT);
        int arrived = __hip_atomic_fetch_add(bar, 1, __ATOMIC_ACQ_REL, __HIP_MEMORY_SCOPE_AGENT);
        if (arrived == NBLK - 1) {
            // all blocks have arrived; safe to reset count before releasing generation
            __hip_atomic_store(bar, 0, __ATOMIC_RELAXED, __HIP_MEMORY_SCOPE_AGENT);
            __hip_atomic_fetch_add(bar + 1, 1, __ATOMIC_ACQ_REL, __HIP_MEMORY_SCOPE_AGENT);
        } else {
            while (__hip_atomic_load(bar + 1, __ATOMIC_ACQUIRE, __HIP_MEMORY_SCOPE_AGENT) == gen)
                __builtin_amdgcn_s_sleep(4);
        }
    }
    __syncthreads();
}

// ---------------- split-bf16 MFMA GEMM + fused score epilogue (device stage) --------
// out[M x 256] = A[M x 256] * B[256 x 256];  B as hi/lo bf16 transposed [n][k].
// AF32=1: A fp32 row-major, converted ONCE per block into LDS hi/lo (shared by 4 waves).
// SC=1: also emit s_t/s_n (per-head dots with avec) — wave w holds head w's 64 cols.
template<int RT, int EPI, int AF32, int SC>
__device__ __forceinline__ void gemm_stage(
    int tile,
    const float* __restrict__ Af,
    const ushort* __restrict__ Ah, const ushort* __restrict__ Al,
    const ushort* __restrict__ Bh, const ushort* __restrict__ Bl,
    const float* __restrict__ bias, const float* __restrict__ avec,
    float* __restrict__ out, float* __restrict__ s_t, float* __restrict__ s_n,
    int M, ushort* sah, ushort* sal)
{
    const int wave = threadIdx.x >> 6;
    const int lane = threadIdx.x & 63;
    const int quad = lane >> 4, l16 = lane & 15;
    const int row0 = tile * (RT * 16);
    const int col0 = wave * 64;

    if (AF32) {
        // cooperative stage: fp32 A tile -> hi/lo bf16 in LDS (once per block)
        for (int idx = threadIdx.x; idx < RT * 16 * 64; idx += 256) {
            int row = idx >> 6, c4 = idx & 63;
            int gr = row0 + row; if (gr >= M) gr = M - 1;
            float4 f = ((const float4*)Af)[gr * 64 + c4];
            ushort4 h, l;
            h.x = f2bf(f.x); l.x = f2bf(f.x - bf2f(h.x));
            h.y = f2bf(f.y); l.y = f2bf(f.y - bf2f(h.y));
            h.z = f2bf(f.z); l.z = f2bf(f.z - bf2f(h.z));
            h.w = f2bf(f.w); l.w = f2bf(f.w - bf2f(h.w));
            *(ushort4*)(&sah[row * LDP + c4 * 4]) = h;
            *(ushort4*)(&sal[row * LDP + c4 * 4]) = l;
        }
        __syncthreads();
    }

    f32x4 acc[RT][4];
#pragma unroll
    for (int r = 0; r < RT; ++r)
#pragma unroll
        for (int c = 0; c < 4; ++c) acc[r][c] = (f32x4){0.f, 0.f, 0.f, 0.f};

    int arow[RT];
#pragma unroll
    for (int r = 0; r < RT; ++r) {
        int rr = row0 + r * 16 + l16;
        arow[r] = (rr < M) ? rr : (M - 1);   // clamp: reads stay in-bounds
    }
    const int kbase = quad * 8;

    for (int k0 = 0; k0 < 256; k0 += 32) {
        bf16x8 a_h[RT], a_l[RT], b_h[4], b_l[4];
#pragma unroll
        for (int r = 0; r < RT; ++r) {
            if (AF32) {
                int loff = (r * 16 + l16) * LDP + k0 + kbase;
                a_h[r] = *(const bf16x8*)(&sah[loff]);   // ds_read_b128, 2-way banks
                a_l[r] = *(const bf16x8*)(&sal[loff]);
            } else {
                int off = arow[r] * 256 + k0 + kbase;
                a_h[r] = *(const bf16x8*)(Ah + off);
                a_l[r] = *(const bf16x8*)(Al + off);
            }
        }
#pragma unroll
        for (int c = 0; c < 4; ++c) {
            int off = (col0 + c * 16 + l16) * 256 + k0 + kbase;
            b_h[c] = *(const bf16x8*)(Bh + off);
            b_l[c] = *(const bf16x8*)(Bl + off);
        }
#pragma unroll
        for (int r = 0; r < RT; ++r)
#pragma unroll
            for (int c = 0; c < 4; ++c) {
                acc[r][c] = __builtin_amdgcn_mfma_f32_16x16x32_bf16(a_h[r], b_h[c], acc[r][c], 0, 0, 0);
                acc[r][c] = __builtin_amdgcn_mfma_f32_16x16x32_bf16(a_h[r], b_l[c], acc[r][c], 0, 0, 0);
                acc[r][c] = __builtin_amdgcn_mfma_f32_16x16x32_bf16(a_l[r], b_h[c], acc[r][c], 0, 0, 0);
            }
    }

    // C/D layout: col = lane&15, row = quad*4 + reg  [measured m89/m91]
#pragma unroll
    for (int r = 0; r < RT; ++r)
#pragma unroll
        for (int c = 0; c < 4; ++c) {
            int col = col0 + c * 16 + l16;
#pragma unroll
            for (int reg = 0; reg < 4; ++reg) {
                int row = row0 + r * 16 + quad * 4 + reg;
                if (row < M) {
                    float v = acc[r][c][reg];
                    if (EPI == 1) v = tanhf(v + bias[col]);
                    out[row * 256 + col] = v;
                }
            }
        }

    if (SC) {
        // head hd == wave; per-lane channels: c*16+l16, c=0..3
        float at[4], an[4];
#pragma unroll
        for (int c = 0; c < 4; ++c) {
            at[c] = avec[wave * 128 + c * 16 + l16];
            an[c] = avec[wave * 128 + 64 + c * 16 + l16];
        }
#pragma unroll
        for (int r = 0; r < RT; ++r) {
            float pt[4] = {0.f, 0.f, 0.f, 0.f}, pn[4] = {0.f, 0.f, 0.f, 0.f};
#pragma unroll
            for (int c = 0; c < 4; ++c)
#pragma unroll
                for (int reg = 0; reg < 4; ++reg) {
                    pt[reg] += acc[r][c][reg] * at[c];
                    pn[reg] += acc[r][c][reg] * an[c];
                }
#pragma unroll
            for (int reg = 0; reg < 4; ++reg)
#pragma unroll
                for (int m = 1; m < 16; m <<= 1) {
                    pt[reg] += __shfl_xor(pt[reg], m);
                    pn[reg] += __shfl_xor(pn[reg], m);
                }
            if (l16 == 0) {
#pragma unroll
                for (int reg = 0; reg < 4; ++reg) {
                    int row = row0 + r * 16 + quad * 4 + reg;
                    if (row < M) {
                        s_t[wave * M + row] = pt[reg];
                        s_n[wave * M + row] = pn[reg];
                    }
                }
            }
        }
    }
}

// ---------------- per-target: wave-parallel dedupe+softmax, float4 aggregate, ELU ---
__device__ __forceinline__ void att_stage(
    int tgt, const float* __restrict__ hprev, const int* __restrict__ nbr_arr,
    const float* __restrict__ s_t, const float* __restrict__ s_n,
    ushort* __restrict__ outhi, ushort* __restrict__ outlo, int T, int Nsrc,
    char* smem)
{
    int* nbr = (int*)smem;                                    // 33 ints   @ 0
    float (*att_s)[DEG + 3] = (float (*)[DEG + 3])(smem + 144);  // 4x35 f32 @ 144
    float4 (*red)[64] = (float4 (*)[64])(smem + 768);         // 4x64 f4   @ 768 (16B aligned)

    const int t = threadIdx.x;
    const int lane = t & 63;
    if (t < DEG) nbr[t] = nbr_arr[tgt * DEG + t];
    else if (t == DEG) nbr[DEG] = nbr_arr[T * DEG + tgt];  // self-loop edge
    __syncthreads();

    {   // wave = head; lane = edge index (33 edges), lanes 33..63 inert
        const int hd = t >> 6;
        int me = (lane <= DEG) ? nbr[lane] : -1;
        int k = (lane <= DEG) ? 1 : 0;
#pragma unroll
        for (int j = 0; j < DEG; ++j) {          // dedupe scan via shuffle
            int v = __shfl(me, j);
            if (j < lane && v == me) k = 0;
        }
        float e = s_t[hd * Nsrc + tgt] + ((lane <= DEG) ? s_n[hd * Nsrc + me] : 0.f);
        e = (e >= 0.f) ? e : ALPHA * e;          // LeakyReLU(0.2)
        float em = k ? e : -1e30f;
        float m = em;
#pragma unroll
        for (int off = 1; off < 64; off <<= 1) m = fmaxf(m, __shfl_xor(m, off));
        float w = k ? __expf(e - m) : 0.f;
        float Z = w;
#pragma unroll
        for (int off = 1; off < 64; off <<= 1) Z += __shfl_xor(Z, off);
        if (lane <= DEG) att_s[hd][lane] = w / Z;
    }
    __syncthreads();

    // aggregation: thread = (rg = t>>6 row-group, cq = t&63 channel-quad)
    const int cq = t & 63;
    const int rg = t >> 6;
    const int hd = cq >> 4;
    const float4* hp4 = (const float4*)hprev;
    float4 acc = make_float4(0.f, 0.f, 0.f, 0.f);
#pragma unroll
    for (int ii = 0; ii < 9; ++ii) {
        int i = rg + ii * 4;
        if (i <= DEG) {
            float w = att_s[hd][i];                       // dup edges: w==0
            float4 v = hp4[(size_t)nbr[i] * 64 + cq];
            acc.x += w * v.x; acc.y += w * v.y;
            acc.z += w * v.z; acc.w += w * v.w;
        }
    }
    red[rg][cq] = acc;
    __syncthreads();
    if (t < 64) {
        float4 s0 = red[0][t], s1 = red[1][t], s2 = red[2][t], s3 = red[3][t];
        float4 s;
        s.x = s0.x + s1.x + s2.x + s3.x;
        s.y = s0.y + s1.y + s2.y + s3.y;
        s.z = s0.z + s1.z + s2.z + s3.z;
        s.w = s0.w + s1.w + s2.w + s3.w;
        s.x = (s.x > 0.f) ? s.x : expm1f(s.x);   // ELU
        s.y = (s.y > 0.f) ? s.y : expm1f(s.y);
        s.z = (s.z > 0.f) ? s.z : expm1f(s.z);
        s.w = (s.w > 0.f) ? s.w : expm1f(s.w);
        ushort4 h, l;
        h.x = f2bf(s.x); l.x = f2bf(s.x - bf2f(h.x));
        h.y = f2bf(s.y); l.y = f2bf(s.y - bf2f(h.y));
        h.z = f2bf(s.z); l.z = f2bf(s.z - bf2f(h.z));
        h.w = f2bf(s.w); l.w = f2bf(s.w - bf2f(h.w));
        ((ushort4*)outhi)[tgt * 64 + t] = h;
        ((ushort4*)outlo)[tgt * 64 + t] = l;
    }
    // NOTE on cross-iteration LDS reuse: nbr/att_s writes of iteration i+1 happen only
    // after this block's own __syncthreads chain; red reads complete before the next
    // red write (which is preceded by two further __syncthreads). Safe without extra sync.
}

// ---------------- fully fused persistent kernel: 6 stages, 5 grid barriers ----------
__global__ __launch_bounds__(256, 3) void fused_kernel(
    const float* __restrict__ x, const float* __restrict__ W0, const float* __restrict__ a0,
    const float* __restrict__ W1, const float* __restrict__ a1,
    const float* __restrict__ linW, const float* __restrict__ linb,
    const int* __restrict__ adj1_nbr, const int* __restrict__ adj0_nbr,
    ushort* Wth, ushort* Wtl, float* st, float* sn, float* h0,
    ushort* xhi, ushort* xlo, float* out, int* bar)
{
    __shared__ __align__(16) char smem[33792];   // union: gemm stage (2x16896) / att arrays (~4.9KB)
    ushort* sah = (ushort*)smem;
    ushort* sal = (ushort*)(smem + 16896);
    const int bid = blockIdx.x;

    // ---- S0: repack weights -> bf16 hi/lo, transposed to [n][k] (3*65536 elems) ----
    for (int g = bid * 256 + threadIdx.x; g < 3 * 65536; g += NBLK * 256) {
        int mat = g >> 16;
        int idx = g & 65535;
        int c = idx >> 8, k = idx & 255;
        float v;
        if (mat == 0)      v = W0[(c >> 6) * (256 * 64) + k * 64 + (c & 63)];
        else if (mat == 1) v = W1[(c >> 6) * (256 * 64) + k * 64 + (c & 63)];
        else               v = linW[c * 256 + k];
        ushort h = f2bf(v);
        Wth[g] = h;
        Wtl[g] = f2bf(v - bf2f(h));
    }
    grid_sync(bar);

    // ---- S1: h0 = x @ Wc0 (fp32 A staged in LDS) + layer-1 scores (500 tiles) ----
    for (int tile = bid; tile < N2C / 32; tile += NBLK)
        gemm_stage<2, 0, 1, 1>(tile, x, nullptr, nullptr, Wth, Wtl, nullptr, a0,
                               h0, st, sn, N2C, sah, sal);
    grid_sync(bar);

    // ---- S2: layer-1 attention (4000 targets) ----
    for (int tgt = bid; tgt < N1C; tgt += NBLK)
        att_stage(tgt, h0, adj1_nbr, st, sn, xhi, xlo, N1C, N2C, smem);
    grid_sync(bar);

    // ---- S3: h1 = x1 @ Wc1 (h1 aliases h0) + layer-2 scores (250 tiles) ----
    for (int tile = bid; tile < N1C / 16; tile += NBLK)
        gemm_stage<1, 0, 0, 1>(tile, nullptr, xhi, xlo, Wth + 65536, Wtl + 65536, nullptr, a1,
                               h0, st, sn, N1C, sah, sal);
    grid_sync(bar);

    // ---- S4: layer-2 attention (1000 targets) ----
    for (int tgt = bid; tgt < N0C; tgt += NBLK)
        att_stage(tgt, h0, adj0_nbr, st, sn, xhi, xlo, N0C, N1C, smem);
    grid_sync(bar);

    // ---- S5: final Linear + Tanh (63 tiles) ----
    for (int tile = bid; tile < (N0C + 15) / 16; tile += NBLK)
        gemm_stage<1, 1, 0, 0>(tile, nullptr, xhi, xlo, Wth + 131072, Wtl + 131072, linb, nullptr,
                               out, nullptr, nullptr, N0C, sah, sal);
}

extern "C" void kernel_launch(void* const* d_in, const int* in_sizes, int n_in,
                              void* d_out, int out_size, void* d_ws, size_t ws_size,
                              hipStream_t stream)
{
    const float* x    = (const float*)d_in[0];
    const float* W0   = (const float*)d_in[1];
    const float* a0   = (const float*)d_in[2];
    const float* W1   = (const float*)d_in[3];
    const float* a1   = (const float*)d_in[4];
    const float* linW = (const float*)d_in[5];
    const float* linb = (const float*)d_in[6];
    const int* adj1_nbr = (const int*)d_in[8];
    const int* adj0_nbr = (const int*)d_in[10];

    char* base = (char*)d_ws;
    int*    bar = (int*)base;                           // 1 KB barrier state (zeroed below)
    ushort* Wth = (ushort*)(base + 1024);               // 3*65536 ushort = 384 KB
    ushort* Wtl = Wth + 3 * 65536;                      // 384 KB          (ends 787456)
    float*  st  = (float*)(base + 787456);              // 4*16000 f32 (padded to 65536)
    float*  sn  = st + 65536;                           //                 (ends 1311744)
    float*  h0  = (float*)(base + 1311744);             // 16000*256 f32 (reused as h1)
    ushort* xhi = (ushort*)(base + 1311744 + 16384000); // att outputs (bf16 hi/lo)
    ushort* xlo = xhi + 4096000;

    // workspace is re-poisoned by the harness each iteration -> barrier must be re-zeroed
    hipMemsetAsync(d_ws, 0, 1024, stream);

    fused_kernel<<<NBLK, 256, 0, stream>>>(
        x, W0, a0, W1, a1, linW, linb, adj1_nbr, adj0_nbr,
        Wth, Wtl, st, sn, h0, xhi, xlo, (float*)d_out, bar);
}

// Round 2
// 527.185 us; speedup vs baseline: 1.8419x; 1.8419x over previous
//
#include <hip/hip_runtime.h>
#include <math.h>

#define N2C 16000
#define N1C 4000
#define N0C 1000
#define DEG 32
#define NHEAD 4
#define ALPHA 0.2f
#define LDP 264     // padded LDS row pitch (ushorts): 264*2=528 B, 16B-aligned, 2-way banks
#define NBLK 768    // 3 blocks/CU x 256 CUs — co-residency proven by round-1 run (it completed)

typedef __attribute__((ext_vector_type(8))) short bf16x8;
typedef __attribute__((ext_vector_type(4))) float f32x4;

__device__ __forceinline__ ushort f2bf(float f) {
    unsigned u = __float_as_uint(f);
    unsigned r = (u + 0x7fffu + ((u >> 16) & 1u)) >> 16;   // RTNE
    return (ushort)r;
}
__device__ __forceinline__ float bf2f(ushort h) {
    return __uint_as_float(((unsigned)h) << 16);
}

// ---- grid-wide sense-reversal barrier ----
// Round-1 lesson: spinning with ACQUIRE at agent scope emits a cache-invalidate per
// poll -> 767 blocks hammer the per-XCD L2s with invalidates -> 938us of stall.
// Fix: RELAXED spin (agent-scope atomic loads still bypass L2 for visibility, no inv),
// then ONE acquire fence after the spin observes the generation flip.
__device__ __forceinline__ void grid_sync(int* bar) {
    __syncthreads();
    if (threadIdx.x == 0) {
        int gen = __hip_atomic_load(bar + 1, __ATOMIC_RELAXED, __HIP_MEMORY_SCOPE_AGENT);
        int arrived = __hip_atomic_fetch_add(bar, 1, __ATOMIC_ACQ_REL, __HIP_MEMORY_SCOPE_AGENT);
        if (arrived == NBLK - 1) {
            // all blocks arrived; reset count before releasing the generation
            __hip_atomic_store(bar, 0, __ATOMIC_RELAXED, __HIP_MEMORY_SCOPE_AGENT);
            __hip_atomic_store(bar + 1, gen + 1, __ATOMIC_RELEASE, __HIP_MEMORY_SCOPE_AGENT);
        } else {
            while (__hip_atomic_load(bar + 1, __ATOMIC_RELAXED, __HIP_MEMORY_SCOPE_AGENT) == gen)
                __builtin_amdgcn_s_sleep(8);   // ~512 cy backoff between polls
            __builtin_amdgcn_fence(__ATOMIC_ACQUIRE, "agent");  // one inv, after exit
        }
    }
    __syncthreads();
}

// ---------------- split-bf16 MFMA GEMM + fused score epilogue (device stage) --------
// out[M x 256] = A[M x 256] * B[256 x 256];  B as hi/lo bf16 transposed [n][k].
// AF32=1: A fp32 row-major, converted ONCE per block into LDS hi/lo (shared by 4 waves).
// SC=1: also emit s_t/s_n (per-head dots with avec) — wave w holds head w's 64 cols.
template<int RT, int EPI, int AF32, int SC>
__device__ __forceinline__ void gemm_stage(
    int tile,
    const float* __restrict__ Af,
    const ushort* __restrict__ Ah, const ushort* __restrict__ Al,
    const ushort* __restrict__ Bh, const ushort* __restrict__ Bl,
    const float* __restrict__ bias, const float* __restrict__ avec,
    float* __restrict__ out, float* __restrict__ s_t, float* __restrict__ s_n,
    int M, ushort* sah, ushort* sal)
{
    const int wave = threadIdx.x >> 6;
    const int lane = threadIdx.x & 63;
    const int quad = lane >> 4, l16 = lane & 15;
    const int row0 = tile * (RT * 16);
    const int col0 = wave * 64;

    if (AF32) {
        // cooperative stage: fp32 A tile -> hi/lo bf16 in LDS (once per block)
        for (int idx = threadIdx.x; idx < RT * 16 * 64; idx += 256) {
            int row = idx >> 6, c4 = idx & 63;
            int gr = row0 + row; if (gr >= M) gr = M - 1;
            float4 f = ((const float4*)Af)[gr * 64 + c4];
            ushort4 h, l;
            h.x = f2bf(f.x); l.x = f2bf(f.x - bf2f(h.x));
            h.y = f2bf(f.y); l.y = f2bf(f.y - bf2f(h.y));
            h.z = f2bf(f.z); l.z = f2bf(f.z - bf2f(h.z));
            h.w = f2bf(f.w); l.w = f2bf(f.w - bf2f(h.w));
            *(ushort4*)(&sah[row * LDP + c4 * 4]) = h;
            *(ushort4*)(&sal[row * LDP + c4 * 4]) = l;
        }
        __syncthreads();
    }

    f32x4 acc[RT][4];
#pragma unroll
    for (int r = 0; r < RT; ++r)
#pragma unroll
        for (int c = 0; c < 4; ++c) acc[r][c] = (f32x4){0.f, 0.f, 0.f, 0.f};

    int arow[RT];
#pragma unroll
    for (int r = 0; r < RT; ++r) {
        int rr = row0 + r * 16 + l16;
        arow[r] = (rr < M) ? rr : (M - 1);   // clamp: reads stay in-bounds
    }
    const int kbase = quad * 8;

    for (int k0 = 0; k0 < 256; k0 += 32) {
        bf16x8 a_h[RT], a_l[RT], b_h[4], b_l[4];
#pragma unroll
        for (int r = 0; r < RT; ++r) {
            if (AF32) {
                int loff = (r * 16 + l16) * LDP + k0 + kbase;
                a_h[r] = *(const bf16x8*)(&sah[loff]);   // ds_read_b128, 2-way banks
                a_l[r] = *(const bf16x8*)(&sal[loff]);
            } else {
                int off = arow[r] * 256 + k0 + kbase;
                a_h[r] = *(const bf16x8*)(Ah + off);
                a_l[r] = *(const bf16x8*)(Al + off);
            }
        }
#pragma unroll
        for (int c = 0; c < 4; ++c) {
            int off = (col0 + c * 16 + l16) * 256 + k0 + kbase;
            b_h[c] = *(const bf16x8*)(Bh + off);
            b_l[c] = *(const bf16x8*)(Bl + off);
        }
#pragma unroll
        for (int r = 0; r < RT; ++r)
#pragma unroll
            for (int c = 0; c < 4; ++c) {
                acc[r][c] = __builtin_amdgcn_mfma_f32_16x16x32_bf16(a_h[r], b_h[c], acc[r][c], 0, 0, 0);
                acc[r][c] = __builtin_amdgcn_mfma_f32_16x16x32_bf16(a_h[r], b_l[c], acc[r][c], 0, 0, 0);
                acc[r][c] = __builtin_amdgcn_mfma_f32_16x16x32_bf16(a_l[r], b_h[c], acc[r][c], 0, 0, 0);
            }
    }

    // C/D layout: col = lane&15, row = quad*4 + reg  [measured m89/m91]
#pragma unroll
    for (int r = 0; r < RT; ++r)
#pragma unroll
        for (int c = 0; c < 4; ++c) {
            int col = col0 + c * 16 + l16;
#pragma unroll
            for (int reg = 0; reg < 4; ++reg) {
                int row = row0 + r * 16 + quad * 4 + reg;
                if (row < M) {
                    float v = acc[r][c][reg];
                    if (EPI == 1) v = tanhf(v + bias[col]);
                    out[row * 256 + col] = v;
                }
            }
        }

    if (SC) {
        // head hd == wave; per-lane channels: c*16+l16, c=0..3
        float at[4], an[4];
#pragma unroll
        for (int c = 0; c < 4; ++c) {
            at[c] = avec[wave * 128 + c * 16 + l16];
            an[c] = avec[wave * 128 + 64 + c * 16 + l16];
        }
#pragma unroll
        for (int r = 0; r < RT; ++r) {
            float pt[4] = {0.f, 0.f, 0.f, 0.f}, pn[4] = {0.f, 0.f, 0.f, 0.f};
#pragma unroll
            for (int c = 0; c < 4; ++c)
#pragma unroll
                for (int reg = 0; reg < 4; ++reg) {
                    pt[reg] += acc[r][c][reg] * at[c];
                    pn[reg] += acc[r][c][reg] * an[c];
                }
#pragma unroll
            for (int reg = 0; reg < 4; ++reg)
#pragma unroll
                for (int m = 1; m < 16; m <<= 1) {
                    pt[reg] += __shfl_xor(pt[reg], m);
                    pn[reg] += __shfl_xor(pn[reg], m);
                }
            if (l16 == 0) {
#pragma unroll
                for (int reg = 0; reg < 4; ++reg) {
                    int row = row0 + r * 16 + quad * 4 + reg;
                    if (row < M) {
                        s_t[wave * M + row] = pt[reg];
                        s_n[wave * M + row] = pn[reg];
                    }
                }
            }
        }
    }
}

// ---------------- per-target: wave-parallel dedupe+softmax, float4 aggregate, ELU ---
__device__ __forceinline__ void att_stage(
    int tgt, const float* __restrict__ hprev, const int* __restrict__ nbr_arr,
    const float* __restrict__ s_t, const float* __restrict__ s_n,
    ushort* __restrict__ outhi, ushort* __restrict__ outlo, int T, int Nsrc,
    char* smem)
{
    int* nbr = (int*)smem;                                    // 33 ints   @ 0
    float (*att_s)[DEG + 3] = (float (*)[DEG + 3])(smem + 144);  // 4x35 f32 @ 144
    float4 (*red)[64] = (float4 (*)[64])(smem + 768);         // 4x64 f4   @ 768 (16B aligned)

    const int t = threadIdx.x;
    const int lane = t & 63;
    if (t < DEG) nbr[t] = nbr_arr[tgt * DEG + t];
    else if (t == DEG) nbr[DEG] = nbr_arr[T * DEG + tgt];  // self-loop edge
    __syncthreads();

    {   // wave = head; lane = edge index (33 edges), lanes 33..63 inert
        const int hd = t >> 6;
        int me = (lane <= DEG) ? nbr[lane] : -1;
        int k = (lane <= DEG) ? 1 : 0;
#pragma unroll
        for (int j = 0; j < DEG; ++j) {          // dedupe scan via shuffle
            int v = __shfl(me, j);
            if (j < lane && v == me) k = 0;
        }
        float e = s_t[hd * Nsrc + tgt] + ((lane <= DEG) ? s_n[hd * Nsrc + me] : 0.f);
        e = (e >= 0.f) ? e : ALPHA * e;          // LeakyReLU(0.2)
        float em = k ? e : -1e30f;
        float m = em;
#pragma unroll
        for (int off = 1; off < 64; off <<= 1) m = fmaxf(m, __shfl_xor(m, off));
        float w = k ? __expf(e - m) : 0.f;
        float Z = w;
#pragma unroll
        for (int off = 1; off < 64; off <<= 1) Z += __shfl_xor(Z, off);
        if (lane <= DEG) att_s[hd][lane] = w / Z;
    }
    __syncthreads();

    // aggregation: thread = (rg = t>>6 row-group, cq = t&63 channel-quad)
    const int cq = t & 63;
    const int rg = t >> 6;
    const int hd = cq >> 4;
    const float4* hp4 = (const float4*)hprev;
    float4 acc = make_float4(0.f, 0.f, 0.f, 0.f);
#pragma unroll
    for (int ii = 0; ii < 9; ++ii) {
        int i = rg + ii * 4;
        if (i <= DEG) {
            float w = att_s[hd][i];                       // dup edges: w==0
            float4 v = hp4[(size_t)nbr[i] * 64 + cq];
            acc.x += w * v.x; acc.y += w * v.y;
            acc.z += w * v.z; acc.w += w * v.w;
        }
    }
    red[rg][cq] = acc;
    __syncthreads();
    if (t < 64) {
        float4 s0 = red[0][t], s1 = red[1][t], s2 = red[2][t], s3 = red[3][t];
        float4 s;
        s.x = s0.x + s1.x + s2.x + s3.x;
        s.y = s0.y + s1.y + s2.y + s3.y;
        s.z = s0.z + s1.z + s2.z + s3.z;
        s.w = s0.w + s1.w + s2.w + s3.w;
        s.x = (s.x > 0.f) ? s.x : expm1f(s.x);   // ELU
        s.y = (s.y > 0.f) ? s.y : expm1f(s.y);
        s.z = (s.z > 0.f) ? s.z : expm1f(s.z);
        s.w = (s.w > 0.f) ? s.w : expm1f(s.w);
        ushort4 h, l;
        h.x = f2bf(s.x); l.x = f2bf(s.x - bf2f(h.x));
        h.y = f2bf(s.y); l.y = f2bf(s.y - bf2f(h.y));
        h.z = f2bf(s.z); l.z = f2bf(s.z - bf2f(h.z));
        h.w = f2bf(s.w); l.w = f2bf(s.w - bf2f(h.w));
        ((ushort4*)outhi)[tgt * 64 + t] = h;
        ((ushort4*)outlo)[tgt * 64 + t] = l;
    }
    // NOTE on cross-iteration LDS reuse: nbr/att_s writes of iteration i+1 happen only
    // after this block's own __syncthreads chain; red reads complete before the next
    // red write (which is preceded by two further __syncthreads). Safe without extra sync.
}

// ---------------- fully fused persistent kernel: 6 stages, 5 grid barriers ----------
__global__ __launch_bounds__(256, 3) void fused_kernel(
    const float* __restrict__ x, const float* __restrict__ W0, const float* __restrict__ a0,
    const float* __restrict__ W1, const float* __restrict__ a1,
    const float* __restrict__ linW, const float* __restrict__ linb,
    const int* __restrict__ adj1_nbr, const int* __restrict__ adj0_nbr,
    ushort* Wth, ushort* Wtl, float* st, float* sn, float* h0,
    ushort* xhi, ushort* xlo, float* out, int* bar)
{
    __shared__ __align__(16) char smem[33792];   // union: gemm stage (2x16896) / att arrays (~4.9KB)
    ushort* sah = (ushort*)smem;
    ushort* sal = (ushort*)(smem + 16896);
    const int bid = blockIdx.x;

    // ---- S0: repack weights -> bf16 hi/lo, transposed to [n][k] (3*65536 elems) ----
    for (int g = bid * 256 + threadIdx.x; g < 3 * 65536; g += NBLK * 256) {
        int mat = g >> 16;
        int idx = g & 65535;
        int c = idx >> 8, k = idx & 255;
        float v;
        if (mat == 0)      v = W0[(c >> 6) * (256 * 64) + k * 64 + (c & 63)];
        else if (mat == 1) v = W1[(c >> 6) * (256 * 64) + k * 64 + (c & 63)];
        else               v = linW[c * 256 + k];
        ushort h = f2bf(v);
        Wth[g] = h;
        Wtl[g] = f2bf(v - bf2f(h));
    }
    grid_sync(bar);

    // ---- S1: h0 = x @ Wc0 (fp32 A staged in LDS) + layer-1 scores (500 tiles) ----
    for (int tile = bid; tile < N2C / 32; tile += NBLK)
        gemm_stage<2, 0, 1, 1>(tile, x, nullptr, nullptr, Wth, Wtl, nullptr, a0,
                               h0, st, sn, N2C, sah, sal);
    grid_sync(bar);

    // ---- S2: layer-1 attention (4000 targets) ----
    for (int tgt = bid; tgt < N1C; tgt += NBLK)
        att_stage(tgt, h0, adj1_nbr, st, sn, xhi, xlo, N1C, N2C, smem);
    grid_sync(bar);

    // ---- S3: h1 = x1 @ Wc1 (h1 aliases h0) + layer-2 scores (250 tiles) ----
    for (int tile = bid; tile < N1C / 16; tile += NBLK)
        gemm_stage<1, 0, 0, 1>(tile, nullptr, xhi, xlo, Wth + 65536, Wtl + 65536, nullptr, a1,
                               h0, st, sn, N1C, sah, sal);
    grid_sync(bar);

    // ---- S4: layer-2 attention (1000 targets) ----
    for (int tgt = bid; tgt < N0C; tgt += NBLK)
        att_stage(tgt, h0, adj0_nbr, st, sn, xhi, xlo, N0C, N1C, smem);
    grid_sync(bar);

    // ---- S5: final Linear + Tanh (63 tiles) ----
    for (int tile = bid; tile < (N0C + 15) / 16; tile += NBLK)
        gemm_stage<1, 1, 0, 0>(tile, nullptr, xhi, xlo, Wth + 131072, Wtl + 131072, linb, nullptr,
                               out, nullptr, nullptr, N0C, sah, sal);
}

extern "C" void kernel_launch(void* const* d_in, const int* in_sizes, int n_in,
                              void* d_out, int out_size, void* d_ws, size_t ws_size,
                              hipStream_t stream)
{
    const float* x    = (const float*)d_in[0];
    const float* W0   = (const float*)d_in[1];
    const float* a0   = (const float*)d_in[2];
    const float* W1   = (const float*)d_in[3];
    const float* a1   = (const float*)d_in[4];
    const float* linW = (const float*)d_in[5];
    const float* linb = (const float*)d_in[6];
    const int* adj1_nbr = (const int*)d_in[8];
    const int* adj0_nbr = (const int*)d_in[10];

    char* base = (char*)d_ws;
    int*    bar = (int*)base;                           // 1 KB barrier state (zeroed below)
    ushort* Wth = (ushort*)(base + 1024);               // 3*65536 ushort = 384 KB
    ushort* Wtl = Wth + 3 * 65536;                      // 384 KB          (ends 787456)
    float*  st  = (float*)(base + 787456);              // 4*16000 f32 (padded to 65536)
    float*  sn  = st + 65536;                           //                 (ends 1311744)
    float*  h0  = (float*)(base + 1311744);             // 16000*256 f32 (reused as h1)
    ushort* xhi = (ushort*)(base + 1311744 + 16384000); // att outputs (bf16 hi/lo)
    ushort* xlo = xhi + 4096000;

    // workspace is re-poisoned by the harness each iteration -> barrier must be re-zeroed
    hipMemsetAsync(d_ws, 0, 1024, stream);

    fused_kernel<<<NBLK, 256, 0, stream>>>(
        x, W0, a0, W1, a1, linW, linb, adj1_nbr, adj0_nbr,
        Wth, Wtl, st, sn, h0, xhi, xlo, (float*)d_out, bar);
}

// Round 3
// 308.473 us; speedup vs baseline: 3.1478x; 1.7090x over previous
//
#include <hip/hip_runtime.h>
#include <math.h>

#define N2C 16000
#define N1C 4000
#define N0C 1000
#define DEG 32
#define NHEAD 4
#define ALPHA 0.2f
#define LDP 264     // padded LDS row pitch (ushorts): 264*2=528 B, 16B-aligned, 2-way banks
#define NBLK 768    // 3 blocks/CU x 256 CUs — co-residency proven (rounds 1-2 completed)
#define NLEAF 24
#define LEAF_SZ 32  // NBLK / NLEAF

typedef __attribute__((ext_vector_type(8))) short bf16x8;
typedef __attribute__((ext_vector_type(4))) float f32x4;

__device__ __forceinline__ ushort f2bf(float f) {
    unsigned u = __float_as_uint(f);
    unsigned r = (u + 0x7fffu + ((u >> 16) & 1u)) >> 16;   // RTNE
    return (ushort)r;
}
__device__ __forceinline__ float bf2f(ushort h) {
    return __uint_as_float(((unsigned)h) << 16);
}

// ---- grid-wide barrier v3: tree arrival + distributed mirrors + monotone epochs ----
// Round-1 lesson: ACQUIRE-spin = per-poll L2 invalidate storm (938us).
// Round-2 lesson: single counter/flag = same-address congestion at the coherence point;
//   768 ACQ_REL RMWs + 767 pollers on ONE line queue behind each other (~80us/barrier).
// v3: (a) one explicit release fence per block (wbL2 — semantically required to move
//   data out of the non-coherent XCD L2), then RELAXED tree arrivals: 24 cacheline-
//   spaced leaf counters x32 arrivals -> 24 root arrivals -> root-last stores epoch to
//   8 mirror lines. (b) pollers distributed across mirrors, RELAXED loads, s_sleep
//   backoff, ONE acquire fence on exit. (c) counters never reset (epochs monotone) —
//   no reuse races; host memsets the 8KB barrier region each launch.
__device__ __forceinline__ void grid_sync(int* bar, int epoch) {
    __syncthreads();   // all 4 waves' stores drained to L2 (vmcnt(0) implied)
    if (threadIdx.x == 0) {
        __builtin_amdgcn_fence(__ATOMIC_RELEASE, "agent");  // wbL2: block's data -> LLC
        const int leaf = blockIdx.x % NLEAF;
        int old = __hip_atomic_fetch_add(&bar[leaf * 32], 1,
                                         __ATOMIC_RELAXED, __HIP_MEMORY_SCOPE_AGENT);
        if (old == epoch * LEAF_SZ - 1) {                   // last of this leaf group
            int oldr = __hip_atomic_fetch_add(&bar[768], 1,
                                              __ATOMIC_RELAXED, __HIP_MEMORY_SCOPE_AGENT);
            if (oldr == epoch * NLEAF - 1) {                // last in grid: release all
#pragma unroll
                for (int j = 0; j < 8; ++j)
                    __hip_atomic_store(&bar[1024 + j * 32], epoch,
                                       __ATOMIC_RELAXED, __HIP_MEMORY_SCOPE_AGENT);
            }
        }
        int* mir = &bar[1024 + (blockIdx.x & 7) * 32];
        while (__hip_atomic_load(mir, __ATOMIC_RELAXED, __HIP_MEMORY_SCOPE_AGENT) < epoch)
            __builtin_amdgcn_s_sleep(16);                   // ~1us backoff between polls
        __builtin_amdgcn_fence(__ATOMIC_ACQUIRE, "agent");  // one inv: see others' data
    }
    __syncthreads();
}

// ---------------- split-bf16 MFMA GEMM + fused score epilogue (device stage) --------
// out[M x 256] = A[M x 256] * B[256 x 256];  B as hi/lo bf16 transposed [n][k].
// AF32=1: A fp32 row-major, converted ONCE per block into LDS hi/lo (shared by 4 waves).
// SC=1: also emit s_t/s_n (per-head dots with avec) — wave w holds head w's 64 cols.
template<int RT, int EPI, int AF32, int SC>
__device__ __forceinline__ void gemm_stage(
    int tile,
    const float* __restrict__ Af,
    const ushort* __restrict__ Ah, const ushort* __restrict__ Al,
    const ushort* __restrict__ Bh, const ushort* __restrict__ Bl,
    const float* __restrict__ bias, const float* __restrict__ avec,
    float* __restrict__ out, float* __restrict__ s_t, float* __restrict__ s_n,
    int M, ushort* sah, ushort* sal)
{
    const int wave = threadIdx.x >> 6;
    const int lane = threadIdx.x & 63;
    const int quad = lane >> 4, l16 = lane & 15;
    const int row0 = tile * (RT * 16);
    const int col0 = wave * 64;

    if (AF32) {
        // cooperative stage: fp32 A tile -> hi/lo bf16 in LDS (once per block)
        for (int idx = threadIdx.x; idx < RT * 16 * 64; idx += 256) {
            int row = idx >> 6, c4 = idx & 63;
            int gr = row0 + row; if (gr >= M) gr = M - 1;
            float4 f = ((const float4*)Af)[gr * 64 + c4];
            ushort4 h, l;
            h.x = f2bf(f.x); l.x = f2bf(f.x - bf2f(h.x));
            h.y = f2bf(f.y); l.y = f2bf(f.y - bf2f(h.y));
            h.z = f2bf(f.z); l.z = f2bf(f.z - bf2f(h.z));
            h.w = f2bf(f.w); l.w = f2bf(f.w - bf2f(h.w));
            *(ushort4*)(&sah[row * LDP + c4 * 4]) = h;
            *(ushort4*)(&sal[row * LDP + c4 * 4]) = l;
        }
        __syncthreads();
    }

    f32x4 acc[RT][4];
#pragma unroll
    for (int r = 0; r < RT; ++r)
#pragma unroll
        for (int c = 0; c < 4; ++c) acc[r][c] = (f32x4){0.f, 0.f, 0.f, 0.f};

    int arow[RT];
#pragma unroll
    for (int r = 0; r < RT; ++r) {
        int rr = row0 + r * 16 + l16;
        arow[r] = (rr < M) ? rr : (M - 1);   // clamp: reads stay in-bounds
    }
    const int kbase = quad * 8;

    for (int k0 = 0; k0 < 256; k0 += 32) {
        bf16x8 a_h[RT], a_l[RT], b_h[4], b_l[4];
#pragma unroll
        for (int r = 0; r < RT; ++r) {
            if (AF32) {
                int loff = (r * 16 + l16) * LDP + k0 + kbase;
                a_h[r] = *(const bf16x8*)(&sah[loff]);   // ds_read_b128, 2-way banks
                a_l[r] = *(const bf16x8*)(&sal[loff]);
            } else {
                int off = arow[r] * 256 + k0 + kbase;
                a_h[r] = *(const bf16x8*)(Ah + off);
                a_l[r] = *(const bf16x8*)(Al + off);
            }
        }
#pragma unroll
        for (int c = 0; c < 4; ++c) {
            int off = (col0 + c * 16 + l16) * 256 + k0 + kbase;
            b_h[c] = *(const bf16x8*)(Bh + off);
            b_l[c] = *(const bf16x8*)(Bl + off);
        }
#pragma unroll
        for (int r = 0; r < RT; ++r)
#pragma unroll
            for (int c = 0; c < 4; ++c) {
                acc[r][c] = __builtin_amdgcn_mfma_f32_16x16x32_bf16(a_h[r], b_h[c], acc[r][c], 0, 0, 0);
                acc[r][c] = __builtin_amdgcn_mfma_f32_16x16x32_bf16(a_h[r], b_l[c], acc[r][c], 0, 0, 0);
                acc[r][c] = __builtin_amdgcn_mfma_f32_16x16x32_bf16(a_l[r], b_h[c], acc[r][c], 0, 0, 0);
            }
    }

    // C/D layout: col = lane&15, row = quad*4 + reg  [measured m89/m91]
#pragma unroll
    for (int r = 0; r < RT; ++r)
#pragma unroll
        for (int c = 0; c < 4; ++c) {
            int col = col0 + c * 16 + l16;
#pragma unroll
            for (int reg = 0; reg < 4; ++reg) {
                int row = row0 + r * 16 + quad * 4 + reg;
                if (row < M) {
                    float v = acc[r][c][reg];
                    if (EPI == 1) v = tanhf(v + bias[col]);
                    out[row * 256 + col] = v;
                }
            }
        }

    if (SC) {
        // head hd == wave; per-lane channels: c*16+l16, c=0..3
        float at[4], an[4];
#pragma unroll
        for (int c = 0; c < 4; ++c) {
            at[c] = avec[wave * 128 + c * 16 + l16];
            an[c] = avec[wave * 128 + 64 + c * 16 + l16];
        }
#pragma unroll
        for (int r = 0; r < RT; ++r) {
            float pt[4] = {0.f, 0.f, 0.f, 0.f}, pn[4] = {0.f, 0.f, 0.f, 0.f};
#pragma unroll
            for (int c = 0; c < 4; ++c)
#pragma unroll
                for (int reg = 0; reg < 4; ++reg) {
                    pt[reg] += acc[r][c][reg] * at[c];
                    pn[reg] += acc[r][c][reg] * an[c];
                }
#pragma unroll
            for (int reg = 0; reg < 4; ++reg)
#pragma unroll
                for (int m = 1; m < 16; m <<= 1) {
                    pt[reg] += __shfl_xor(pt[reg], m);
                    pn[reg] += __shfl_xor(pn[reg], m);
                }
            if (l16 == 0) {
#pragma unroll
                for (int reg = 0; reg < 4; ++reg) {
                    int row = row0 + r * 16 + quad * 4 + reg;
                    if (row < M) {
                        s_t[wave * M + row] = pt[reg];
                        s_n[wave * M + row] = pn[reg];
                    }
                }
            }
        }
    }
}

// ---------------- per-target: wave-parallel dedupe+softmax, float4 aggregate, ELU ---
__device__ __forceinline__ void att_stage(
    int tgt, const float* __restrict__ hprev, const int* __restrict__ nbr_arr,
    const float* __restrict__ s_t, const float* __restrict__ s_n,
    ushort* __restrict__ outhi, ushort* __restrict__ outlo, int T, int Nsrc,
    char* smem)
{
    int* nbr = (int*)smem;                                    // 33 ints   @ 0
    float (*att_s)[DEG + 3] = (float (*)[DEG + 3])(smem + 144);  // 4x35 f32 @ 144
    float4 (*red)[64] = (float4 (*)[64])(smem + 768);         // 4x64 f4   @ 768 (16B aligned)

    const int t = threadIdx.x;
    const int lane = t & 63;
    if (t < DEG) nbr[t] = nbr_arr[tgt * DEG + t];
    else if (t == DEG) nbr[DEG] = nbr_arr[T * DEG + tgt];  // self-loop edge
    __syncthreads();

    {   // wave = head; lane = edge index (33 edges), lanes 33..63 inert
        const int hd = t >> 6;
        int me = (lane <= DEG) ? nbr[lane] : -1;
        int k = (lane <= DEG) ? 1 : 0;
#pragma unroll
        for (int j = 0; j < DEG; ++j) {          // dedupe scan via shuffle
            int v = __shfl(me, j);
            if (j < lane && v == me) k = 0;
        }
        float e = s_t[hd * Nsrc + tgt] + ((lane <= DEG) ? s_n[hd * Nsrc + me] : 0.f);
        e = (e >= 0.f) ? e : ALPHA * e;          // LeakyReLU(0.2)
        float em = k ? e : -1e30f;
        float m = em;
#pragma unroll
        for (int off = 1; off < 64; off <<= 1) m = fmaxf(m, __shfl_xor(m, off));
        float w = k ? __expf(e - m) : 0.f;
        float Z = w;
#pragma unroll
        for (int off = 1; off < 64; off <<= 1) Z += __shfl_xor(Z, off);
        if (lane <= DEG) att_s[hd][lane] = w / Z;
    }
    __syncthreads();

    // aggregation: thread = (rg = t>>6 row-group, cq = t&63 channel-quad)
    const int cq = t & 63;
    const int rg = t >> 6;
    const int hd = cq >> 4;
    const float4* hp4 = (const float4*)hprev;
    float4 acc = make_float4(0.f, 0.f, 0.f, 0.f);
#pragma unroll
    for (int ii = 0; ii < 9; ++ii) {
        int i = rg + ii * 4;
        if (i <= DEG) {
            float w = att_s[hd][i];                       // dup edges: w==0
            float4 v = hp4[(size_t)nbr[i] * 64 + cq];
            acc.x += w * v.x; acc.y += w * v.y;
            acc.z += w * v.z; acc.w += w * v.w;
        }
    }
    red[rg][cq] = acc;
    __syncthreads();
    if (t < 64) {
        float4 s0 = red[0][t], s1 = red[1][t], s2 = red[2][t], s3 = red[3][t];
        float4 s;
        s.x = s0.x + s1.x + s2.x + s3.x;
        s.y = s0.y + s1.y + s2.y + s3.y;
        s.z = s0.z + s1.z + s2.z + s3.z;
        s.w = s0.w + s1.w + s2.w + s3.w;
        s.x = (s.x > 0.f) ? s.x : expm1f(s.x);   // ELU
        s.y = (s.y > 0.f) ? s.y : expm1f(s.y);
        s.z = (s.z > 0.f) ? s.z : expm1f(s.z);
        s.w = (s.w > 0.f) ? s.w : expm1f(s.w);
        ushort4 h, l;
        h.x = f2bf(s.x); l.x = f2bf(s.x - bf2f(h.x));
        h.y = f2bf(s.y); l.y = f2bf(s.y - bf2f(h.y));
        h.z = f2bf(s.z); l.z = f2bf(s.z - bf2f(h.z));
        h.w = f2bf(s.w); l.w = f2bf(s.w - bf2f(h.w));
        ((ushort4*)outhi)[tgt * 64 + t] = h;
        ((ushort4*)outlo)[tgt * 64 + t] = l;
    }
    // NOTE on cross-iteration LDS reuse: nbr/att_s writes of iteration i+1 happen only
    // after this block's own __syncthreads chain; red reads complete before the next
    // red write (which is preceded by two further __syncthreads). Safe without extra sync.
}

// ---------------- fully fused persistent kernel: 6 stages, 5 grid barriers ----------
__global__ __launch_bounds__(256, 3) void fused_kernel(
    const float* __restrict__ x, const float* __restrict__ W0, const float* __restrict__ a0,
    const float* __restrict__ W1, const float* __restrict__ a1,
    const float* __restrict__ linW, const float* __restrict__ linb,
    const int* __restrict__ adj1_nbr, const int* __restrict__ adj0_nbr,
    ushort* Wth, ushort* Wtl, float* st, float* sn, float* h0,
    ushort* xhi, ushort* xlo, float* out, int* bar)
{
    __shared__ __align__(16) char smem[33792];   // union: gemm stage (2x16896) / att arrays (~4.9KB)
    ushort* sah = (ushort*)smem;
    ushort* sal = (ushort*)(smem + 16896);
    const int bid = blockIdx.x;

    // ---- S0: repack weights -> bf16 hi/lo, transposed to [n][k] (3*65536 elems) ----
    for (int g = bid * 256 + threadIdx.x; g < 3 * 65536; g += NBLK * 256) {
        int mat = g >> 16;
        int idx = g & 65535;
        int c = idx >> 8, k = idx & 255;
        float v;
        if (mat == 0)      v = W0[(c >> 6) * (256 * 64) + k * 64 + (c & 63)];
        else if (mat == 1) v = W1[(c >> 6) * (256 * 64) + k * 64 + (c & 63)];
        else               v = linW[c * 256 + k];
        ushort h = f2bf(v);
        Wth[g] = h;
        Wtl[g] = f2bf(v - bf2f(h));
    }
    grid_sync(bar, 1);

    // ---- S1: h0 = x @ Wc0 (fp32 A staged in LDS) + layer-1 scores (500 tiles) ----
    for (int tile = bid; tile < N2C / 32; tile += NBLK)
        gemm_stage<2, 0, 1, 1>(tile, x, nullptr, nullptr, Wth, Wtl, nullptr, a0,
                               h0, st, sn, N2C, sah, sal);
    grid_sync(bar, 2);

    // ---- S2: layer-1 attention (4000 targets) ----
    for (int tgt = bid; tgt < N1C; tgt += NBLK)
        att_stage(tgt, h0, adj1_nbr, st, sn, xhi, xlo, N1C, N2C, smem);
    grid_sync(bar, 3);

    // ---- S3: h1 = x1 @ Wc1 (h1 aliases h0) + layer-2 scores (250 tiles) ----
    for (int tile = bid; tile < N1C / 16; tile += NBLK)
        gemm_stage<1, 0, 0, 1>(tile, nullptr, xhi, xlo, Wth + 65536, Wtl + 65536, nullptr, a1,
                               h0, st, sn, N1C, sah, sal);
    grid_sync(bar, 4);

    // ---- S4: layer-2 attention (1000 targets) ----
    for (int tgt = bid; tgt < N0C; tgt += NBLK)
        att_stage(tgt, h0, adj0_nbr, st, sn, xhi, xlo, N0C, N1C, smem);
    grid_sync(bar, 5);

    // ---- S5: final Linear + Tanh (63 tiles) ----
    for (int tile = bid; tile < (N0C + 15) / 16; tile += NBLK)
        gemm_stage<1, 1, 0, 0>(tile, nullptr, xhi, xlo, Wth + 131072, Wtl + 131072, linb, nullptr,
                               out, nullptr, nullptr, N0C, sah, sal);
}

extern "C" void kernel_launch(void* const* d_in, const int* in_sizes, int n_in,
                              void* d_out, int out_size, void* d_ws, size_t ws_size,
                              hipStream_t stream)
{
    const float* x    = (const float*)d_in[0];
    const float* W0   = (const float*)d_in[1];
    const float* a0   = (const float*)d_in[2];
    const float* W1   = (const float*)d_in[3];
    const float* a1   = (const float*)d_in[4];
    const float* linW = (const float*)d_in[5];
    const float* linb = (const float*)d_in[6];
    const int* adj1_nbr = (const int*)d_in[8];
    const int* adj0_nbr = (const int*)d_in[10];

    char* base = (char*)d_ws;
    int*    bar = (int*)base;                           // 8 KB barrier region (zeroed below)
                                                        //  leaves: bar[i*32], i<24
                                                        //  root:   bar[768]
                                                        //  mirrors bar[1024+j*32], j<8
    ushort* Wth = (ushort*)(base + 8192);               // 3*65536 ushort = 384 KB
    ushort* Wtl = Wth + 3 * 65536;                      // 384 KB
    float*  st  = (float*)(base + 794624);              // 4*16000 f32 (padded to 65536)
    float*  sn  = st + 65536;
    float*  h0  = (float*)(base + 1318912);             // 16000*256 f32 (reused as h1)
    ushort* xhi = (ushort*)(base + 1318912 + 16384000); // att outputs (bf16 hi/lo)
    ushort* xlo = xhi + 1024000;                        // 4000*256 ushorts each

    // workspace is re-poisoned by the harness each iteration -> barrier must be re-zeroed
    hipMemsetAsync(d_ws, 0, 8192, stream);

    fused_kernel<<<NBLK, 256, 0, stream>>>(
        x, W0, a0, W1, a1, linW, linb, adj1_nbr, adj0_nbr,
        Wth, Wtl, st, sn, h0, xhi, xlo, (float*)d_out, bar);
}

// Round 4
// 175.942 us; speedup vs baseline: 5.5189x; 1.7533x over previous
//
#include <hip/hip_runtime.h>
#include <math.h>

#define N2C 16000
#define N1C 4000
#define N0C 1000
#define DEG 32
#define NHEAD 4
#define ALPHA 0.2f
#define LDP 264     // padded LDS row pitch (ushorts): 264*2=528 B, 16B-aligned, 2-way banks

typedef __attribute__((ext_vector_type(8))) short bf16x8;
typedef __attribute__((ext_vector_type(4))) float f32x4;

__device__ __forceinline__ ushort f2bf(float f) {
    unsigned u = __float_as_uint(f);
    unsigned r = (u + 0x7fffu + ((u >> 16) & 1u)) >> 16;   // RTNE
    return (ushort)r;
}
__device__ __forceinline__ float bf2f(ushort h) {
    return __uint_as_float(((unsigned)h) << 16);
}

// ---------------- K0: repack weights -> bf16 hi/lo, transposed to [n][k] ------------
__global__ __launch_bounds__(256) void repack_kernel(
    const float* __restrict__ W0, const float* __restrict__ W1,
    const float* __restrict__ linW,
    ushort* __restrict__ Wth, ushort* __restrict__ Wtl)
{
    int g = blockIdx.x * 256 + threadIdx.x;   // 0 .. 3*65536-1
    int mat = g >> 16;
    int idx = g & 65535;
    int c = idx >> 8, k = idx & 255;
    float v;
    if (mat == 0)      v = W0[(c >> 6) * (256 * 64) + k * 64 + (c & 63)];
    else if (mat == 1) v = W1[(c >> 6) * (256 * 64) + k * 64 + (c & 63)];
    else               v = linW[c * 256 + k];
    ushort h = f2bf(v);
    __builtin_nontemporal_store(h, &Wth[g]);                     // no dirty-L2 buildup
    __builtin_nontemporal_store(f2bf(v - bf2f(h)), &Wtl[g]);
}

// ---------------- K1: h0 = x @ Wc0 (split-bf16 MFMA) + layer-1 scores --------------
// A fp32 staged+converted once per block into LDS hi/lo; 500 blocks x 32 rows.
__global__ __launch_bounds__(256) void gemm1_kernel(
    const float* __restrict__ Af,
    const ushort* __restrict__ Bh, const ushort* __restrict__ Bl,
    const float* __restrict__ avec,
    float* __restrict__ out, float* __restrict__ s_t, float* __restrict__ s_n)
{
    __shared__ ushort sah[32 * LDP];
    __shared__ ushort sal[32 * LDP];
    const int wave = threadIdx.x >> 6, lane = threadIdx.x & 63;
    const int quad = lane >> 4, l16 = lane & 15;
    const int row0 = blockIdx.x * 32;            // 500*32 = 16000 exactly, no clamp
    const int col0 = wave * 64;

    for (int idx = threadIdx.x; idx < 32 * 64; idx += 256) {
        int row = idx >> 6, c4 = idx & 63;
        float4 f = ((const float4*)Af)[(size_t)(row0 + row) * 64 + c4];
        ushort4 h, l;
        h.x = f2bf(f.x); l.x = f2bf(f.x - bf2f(h.x));
        h.y = f2bf(f.y); l.y = f2bf(f.y - bf2f(h.y));
        h.z = f2bf(f.z); l.z = f2bf(f.z - bf2f(h.z));
        h.w = f2bf(f.w); l.w = f2bf(f.w - bf2f(h.w));
        *(ushort4*)(&sah[row * LDP + c4 * 4]) = h;
        *(ushort4*)(&sal[row * LDP + c4 * 4]) = l;
    }
    __syncthreads();

    f32x4 acc[2][4];
#pragma unroll
    for (int r = 0; r < 2; ++r)
#pragma unroll
        for (int c = 0; c < 4; ++c) acc[r][c] = (f32x4){0.f, 0.f, 0.f, 0.f};
    const int kbase = quad * 8;

    for (int k0 = 0; k0 < 256; k0 += 32) {
        bf16x8 a_h[2], a_l[2], b_h[4], b_l[4];
#pragma unroll
        for (int r = 0; r < 2; ++r) {
            int loff = (r * 16 + l16) * LDP + k0 + kbase;
            a_h[r] = *(const bf16x8*)(&sah[loff]);
            a_l[r] = *(const bf16x8*)(&sal[loff]);
        }
#pragma unroll
        for (int c = 0; c < 4; ++c) {
            int off = (col0 + c * 16 + l16) * 256 + k0 + kbase;
            b_h[c] = *(const bf16x8*)(Bh + off);
            b_l[c] = *(const bf16x8*)(Bl + off);
        }
#pragma unroll
        for (int r = 0; r < 2; ++r)
#pragma unroll
            for (int c = 0; c < 4; ++c) {
                acc[r][c] = __builtin_amdgcn_mfma_f32_16x16x32_bf16(a_h[r], b_h[c], acc[r][c], 0, 0, 0);
                acc[r][c] = __builtin_amdgcn_mfma_f32_16x16x32_bf16(a_h[r], b_l[c], acc[r][c], 0, 0, 0);
                acc[r][c] = __builtin_amdgcn_mfma_f32_16x16x32_bf16(a_l[r], b_h[c], acc[r][c], 0, 0, 0);
            }
    }

    // C/D layout: col = lane&15, row = quad*4 + reg  [measured m89/m91]
#pragma unroll
    for (int r = 0; r < 2; ++r)
#pragma unroll
        for (int c = 0; c < 4; ++c) {
            int col = col0 + c * 16 + l16;
#pragma unroll
            for (int reg = 0; reg < 4; ++reg) {
                int row = row0 + r * 16 + quad * 4 + reg;
                __builtin_nontemporal_store(acc[r][c][reg], &out[(size_t)row * 256 + col]);
            }
        }

    // fused layer-1 scores: head == wave
    float at[4], an[4];
#pragma unroll
    for (int c = 0; c < 4; ++c) {
        at[c] = avec[wave * 128 + c * 16 + l16];
        an[c] = avec[wave * 128 + 64 + c * 16 + l16];
    }
#pragma unroll
    for (int r = 0; r < 2; ++r) {
        float pt[4] = {0.f, 0.f, 0.f, 0.f}, pn[4] = {0.f, 0.f, 0.f, 0.f};
#pragma unroll
        for (int c = 0; c < 4; ++c)
#pragma unroll
            for (int reg = 0; reg < 4; ++reg) {
                pt[reg] += acc[r][c][reg] * at[c];
                pn[reg] += acc[r][c][reg] * an[c];
            }
#pragma unroll
        for (int reg = 0; reg < 4; ++reg)
#pragma unroll
            for (int m = 1; m < 16; m <<= 1) {
                pt[reg] += __shfl_xor(pt[reg], m);
                pn[reg] += __shfl_xor(pn[reg], m);
            }
        if (l16 == 0) {
#pragma unroll
            for (int reg = 0; reg < 4; ++reg) {
                int row = row0 + r * 16 + quad * 4 + reg;
                __builtin_nontemporal_store(pt[reg], &s_t[wave * N2C + row]);
                __builtin_nontemporal_store(pn[reg], &s_n[wave * N2C + row]);
            }
        }
    }
}

// ---------------- K2: att1 (dedupe+softmax+gather+ELU) fused with gemm2 + scores ----
// One block = one 16-row gemm tile = 16 attention targets; 250 blocks.
// Wave w computes targets w*4..w*4+3 (softmax wave-parallel, lane = edge).
__global__ __launch_bounds__(256) void att_gemm_kernel(
    const float* __restrict__ h0, const int* __restrict__ nbr_arr,
    const float* __restrict__ s_t, const float* __restrict__ s_n,
    const ushort* __restrict__ Bh, const ushort* __restrict__ Bl,
    const float* __restrict__ avec,
    float* __restrict__ h1, float* __restrict__ st2, float* __restrict__ sn2)
{
    __shared__ ushort sah[16 * LDP];
    __shared__ ushort sal[16 * LDP];
    __shared__ int   nbr_s[16][DEG + 1];
    __shared__ float att_w[16][NHEAD][DEG + 1];

    const int wave = threadIdx.x >> 6, lane = threadIdx.x & 63;
    const int quad = lane >> 4, l16 = lane & 15;
    const int row0 = blockIdx.x * 16;            // 250*16 = 4000 exactly

    for (int idx = threadIdx.x; idx < 16 * (DEG + 1); idx += 256) {
        int tt = idx / (DEG + 1), e = idx - tt * (DEG + 1);
        nbr_s[tt][e] = (e < DEG) ? nbr_arr[(row0 + tt) * DEG + e]
                                 : nbr_arr[N1C * DEG + row0 + tt];   // self-loop edge
    }
    __syncthreads();

    for (int i = 0; i < 4; ++i) {
        const int tl = wave * 4 + i;
        const int gt = row0 + tl;
        int me = (lane <= DEG) ? nbr_s[tl][lane] : 0;
        int k = (lane <= DEG) ? 1 : 0;
#pragma unroll
        for (int j = 0; j < DEG; ++j) {          // dedupe scan via shuffle
            int v = __shfl(me, j);
            if (j < lane && v == me) k = 0;
        }
#pragma unroll
        for (int hd = 0; hd < NHEAD; ++hd) {
            float e = s_t[hd * N2C + gt] + s_n[hd * N2C + me];
            e = (e >= 0.f) ? e : ALPHA * e;      // LeakyReLU(0.2)
            float em = k ? e : -1e30f;
            float m = em;
#pragma unroll
            for (int off = 1; off < 64; off <<= 1) m = fmaxf(m, __shfl_xor(m, off));
            float w = k ? __expf(e - m) : 0.f;
            float Z = w;
#pragma unroll
            for (int off = 1; off < 64; off <<= 1) Z += __shfl_xor(Z, off);
            if (lane <= DEG) att_w[tl][hd][lane] = w / Z;
        }
        __syncthreads();   // att_w cross-lane LDS visibility (uniform: all waves hit it)

        // aggregation: lane = channel-quad (4 ch), head of channels = lane>>4
        const int hh = lane >> 4;
        float4 acc = make_float4(0.f, 0.f, 0.f, 0.f);
#pragma unroll
        for (int e = 0; e <= DEG; ++e) {
            float w = att_w[tl][hh][e];          // dup edges: w==0
            float4 v = ((const float4*)h0)[(size_t)nbr_s[tl][e] * 64 + lane];
            acc.x += w * v.x; acc.y += w * v.y;
            acc.z += w * v.z; acc.w += w * v.w;
        }
        acc.x = (acc.x > 0.f) ? acc.x : expm1f(acc.x);   // ELU
        acc.y = (acc.y > 0.f) ? acc.y : expm1f(acc.y);
        acc.z = (acc.z > 0.f) ? acc.z : expm1f(acc.z);
        acc.w = (acc.w > 0.f) ? acc.w : expm1f(acc.w);
        ushort4 h4, l4;
        h4.x = f2bf(acc.x); l4.x = f2bf(acc.x - bf2f(h4.x));
        h4.y = f2bf(acc.y); l4.y = f2bf(acc.y - bf2f(h4.y));
        h4.z = f2bf(acc.z); l4.z = f2bf(acc.z - bf2f(h4.z));
        h4.w = f2bf(acc.w); l4.w = f2bf(acc.w - bf2f(h4.w));
        *(ushort4*)(&sah[tl * LDP + lane * 4]) = h4;
        *(ushort4*)(&sal[tl * LDP + lane * 4]) = l4;
    }
    __syncthreads();

    // ---- gemm2: 16 rows x 256 cols, A from LDS hi/lo, split-bf16 MFMA ----
    f32x4 acc2[4];
#pragma unroll
    for (int c = 0; c < 4; ++c) acc2[c] = (f32x4){0.f, 0.f, 0.f, 0.f};
    const int col0 = wave * 64;
    const int kbase = quad * 8;
    for (int k0 = 0; k0 < 256; k0 += 32) {
        bf16x8 a_h, a_l, b_h[4], b_l[4];
        int loff = l16 * LDP + k0 + kbase;
        a_h = *(const bf16x8*)(&sah[loff]);
        a_l = *(const bf16x8*)(&sal[loff]);
#pragma unroll
        for (int c = 0; c < 4; ++c) {
            int off = (col0 + c * 16 + l16) * 256 + k0 + kbase;
            b_h[c] = *(const bf16x8*)(Bh + off);
            b_l[c] = *(const bf16x8*)(Bl + off);
        }
#pragma unroll
        for (int c = 0; c < 4; ++c) {
            acc2[c] = __builtin_amdgcn_mfma_f32_16x16x32_bf16(a_h, b_h[c], acc2[c], 0, 0, 0);
            acc2[c] = __builtin_amdgcn_mfma_f32_16x16x32_bf16(a_h, b_l[c], acc2[c], 0, 0, 0);
            acc2[c] = __builtin_amdgcn_mfma_f32_16x16x32_bf16(a_l, b_h[c], acc2[c], 0, 0, 0);
        }
    }
#pragma unroll
    for (int c = 0; c < 4; ++c) {
        int col = col0 + c * 16 + l16;
#pragma unroll
        for (int reg = 0; reg < 4; ++reg) {
            int row = row0 + quad * 4 + reg;
            __builtin_nontemporal_store(acc2[c][reg], &h1[(size_t)row * 256 + col]);
        }
    }

    // fused layer-2 scores (head == wave)
    float at[4], an[4];
#pragma unroll
    for (int c = 0; c < 4; ++c) {
        at[c] = avec[wave * 128 + c * 16 + l16];
        an[c] = avec[wave * 128 + 64 + c * 16 + l16];
    }
    float pt[4] = {0.f, 0.f, 0.f, 0.f}, pn[4] = {0.f, 0.f, 0.f, 0.f};
#pragma unroll
    for (int c = 0; c < 4; ++c)
#pragma unroll
        for (int reg = 0; reg < 4; ++reg) {
            pt[reg] += acc2[c][reg] * at[c];
            pn[reg] += acc2[c][reg] * an[c];
        }
#pragma unroll
    for (int reg = 0; reg < 4; ++reg)
#pragma unroll
        for (int m = 1; m < 16; m <<= 1) {
            pt[reg] += __shfl_xor(pt[reg], m);
            pn[reg] += __shfl_xor(pn[reg], m);
        }
    if (l16 == 0) {
#pragma unroll
        for (int reg = 0; reg < 4; ++reg) {
            int row = row0 + quad * 4 + reg;
            __builtin_nontemporal_store(pt[reg], &st2[wave * N1C + row]);
            __builtin_nontemporal_store(pn[reg], &sn2[wave * N1C + row]);
        }
    }
}

// ---------------- K3: att2 + final Linear + Tanh (4 targets/block, wave = target) ---
__global__ __launch_bounds__(256) void att_lin_kernel(
    const float* __restrict__ h1, const int* __restrict__ nbr_arr,
    const float* __restrict__ s_t, const float* __restrict__ s_n,
    const ushort* __restrict__ Bh, const ushort* __restrict__ Bl,
    const float* __restrict__ bias, float* __restrict__ out)
{
    __shared__ int   nbr_s[4][DEG + 1];
    __shared__ float att_w[4][NHEAD][DEG + 1];
    __shared__ float x2[4][256];

    const int wave = threadIdx.x >> 6, lane = threadIdx.x & 63;
    const int blk = blockIdx.x;                  // 250 blocks * 4 targets = 1000

    for (int idx = threadIdx.x; idx < 4 * (DEG + 1); idx += 256) {
        int tt = idx / (DEG + 1), e = idx - tt * (DEG + 1);
        nbr_s[tt][e] = (e < DEG) ? nbr_arr[(blk * 4 + tt) * DEG + e]
                                 : nbr_arr[N0C * DEG + blk * 4 + tt];
    }
    __syncthreads();

    {
        const int tl = wave;
        const int gt = blk * 4 + tl;
        int me = (lane <= DEG) ? nbr_s[tl][lane] : 0;
        int k = (lane <= DEG) ? 1 : 0;
#pragma unroll
        for (int j = 0; j < DEG; ++j) {
            int v = __shfl(me, j);
            if (j < lane && v == me) k = 0;
        }
#pragma unroll
        for (int hd = 0; hd < NHEAD; ++hd) {
            float e = s_t[hd * N1C + gt] + s_n[hd * N1C + me];
            e = (e >= 0.f) ? e : ALPHA * e;
            float em = k ? e : -1e30f;
            float m = em;
#pragma unroll
            for (int off = 1; off < 64; off <<= 1) m = fmaxf(m, __shfl_xor(m, off));
            float w = k ? __expf(e - m) : 0.f;
            float Z = w;
#pragma unroll
            for (int off = 1; off < 64; off <<= 1) Z += __shfl_xor(Z, off);
            if (lane <= DEG) att_w[tl][hd][lane] = w / Z;
        }
    }
    __syncthreads();
    {
        const int tl = wave;
        const int hh = lane >> 4;
        float4 acc = make_float4(0.f, 0.f, 0.f, 0.f);
#pragma unroll
        for (int e = 0; e <= DEG; ++e) {
            float w = att_w[tl][hh][e];
            float4 v = ((const float4*)h1)[(size_t)nbr_s[tl][e] * 64 + lane];
            acc.x += w * v.x; acc.y += w * v.y;
            acc.z += w * v.z; acc.w += w * v.w;
        }
        acc.x = (acc.x > 0.f) ? acc.x : expm1f(acc.x);   // ELU
        acc.y = (acc.y > 0.f) ? acc.y : expm1f(acc.y);
        acc.z = (acc.z > 0.f) ? acc.z : expm1f(acc.z);
        acc.w = (acc.w > 0.f) ? acc.w : expm1f(acc.w);
        *(float4*)(&x2[tl][lane * 4]) = acc;
    }
    __syncthreads();

    // final linear: thread = output channel c; fp32 matvec vs (Bh+Bl) rows [c][k]
    const int c = threadIdx.x;
    float v0 = 0.f, v1 = 0.f, v2 = 0.f, v3 = 0.f;
    for (int k8 = 0; k8 < 32; ++k8) {
        bf16x8 hb = *(const bf16x8*)(Bh + c * 256 + k8 * 8);
        bf16x8 lb = *(const bf16x8*)(Bl + c * 256 + k8 * 8);
#pragma unroll
        for (int j = 0; j < 8; ++j) {
            float wv = bf2f((ushort)hb[j]) + bf2f((ushort)lb[j]);
            int kk = k8 * 8 + j;
            v0 += x2[0][kk] * wv; v1 += x2[1][kk] * wv;
            v2 += x2[2][kk] * wv; v3 += x2[3][kk] * wv;
        }
    }
    float b = bias[c];
    out[(size_t)(blk * 4 + 0) * 256 + c] = tanhf(v0 + b);
    out[(size_t)(blk * 4 + 1) * 256 + c] = tanhf(v1 + b);
    out[(size_t)(blk * 4 + 2) * 256 + c] = tanhf(v2 + b);
    out[(size_t)(blk * 4 + 3) * 256 + c] = tanhf(v3 + b);
}

extern "C" void kernel_launch(void* const* d_in, const int* in_sizes, int n_in,
                              void* d_out, int out_size, void* d_ws, size_t ws_size,
                              hipStream_t stream)
{
    const float* x    = (const float*)d_in[0];
    const float* W0   = (const float*)d_in[1];
    const float* a0   = (const float*)d_in[2];
    const float* W1   = (const float*)d_in[3];
    const float* a1   = (const float*)d_in[4];
    const float* linW = (const float*)d_in[5];
    const float* linb = (const float*)d_in[6];
    const int* adj1_nbr = (const int*)d_in[8];
    const int* adj0_nbr = (const int*)d_in[10];

    char* base = (char*)d_ws;
    ushort* Wth = (ushort*)base;                 // 3*65536 ushort = 384 KB
    ushort* Wtl = Wth + 3 * 65536;               // 384 KB          (ends 786432)
    float*  st  = (float*)(base + 786432);       // 4*16000 f32 (padded slot 256 KB)
    float*  sn  = (float*)(base + 1048576);      //                 (ends 1310720)
    float*  st2 = (float*)(base + 1310720);      // 4*4000 f32 (64 KB slot)
    float*  sn2 = (float*)(base + 1376256);      //                 (ends 1441792)
    float*  h0  = (float*)(base + 1441792);      // 16000*256 f32 = 16 MB
    float*  h1  = (float*)(base + 17825792);     // 4000*256 f32 = 4 MB (ends ~21.9 MB)

    // K0: weight repack (bf16 hi/lo, [n][k])
    repack_kernel<<<768, 256, 0, stream>>>(W0, W1, linW, Wth, Wtl);

    // K1: h0 = x @ Wc0 + layer-1 scores
    gemm1_kernel<<<N2C / 32, 256, 0, stream>>>(x, Wth, Wtl, a0, h0, st, sn);

    // K2: att1 -> gemm2 (h1) + layer-2 scores, fused
    att_gemm_kernel<<<N1C / 16, 256, 0, stream>>>(
        h0, adj1_nbr, st, sn, Wth + 65536, Wtl + 65536, a1, h1, st2, sn2);

    // K3: att2 -> Linear+Tanh, fused
    att_lin_kernel<<<N0C / 4, 256, 0, stream>>>(
        h1, adj0_nbr, st2, sn2, Wth + 131072, Wtl + 131072, linb, (float*)d_out);
}

// Round 6
// 157.746 us; speedup vs baseline: 6.1555x; 1.1153x over previous
//
#include <hip/hip_runtime.h>
#include <math.h>

#define N2C 16000
#define N1C 4000
#define N0C 1000
#define DEG 32
#define NHEAD 4
#define ALPHA 0.2f
#define LDP 264     // padded LDS row pitch (ushorts): 264*2=528 B, 16B-aligned, 2-way banks

typedef __attribute__((ext_vector_type(8))) short bf16x8;
typedef __attribute__((ext_vector_type(4))) float f32x4;

__device__ __forceinline__ ushort f2bf(float f) {
    unsigned u = __float_as_uint(f);
    unsigned r = (u + 0x7fffu + ((u >> 16) & 1u)) >> 16;   // RTNE
    return (ushort)r;
}
__device__ __forceinline__ float bf2f(ushort h) {
    return __uint_as_float(((unsigned)h) << 16);
}
__device__ __forceinline__ unsigned long long pack4(ushort a, ushort b, ushort c, ushort d) {
    return (unsigned long long)a | ((unsigned long long)b << 16) |
           ((unsigned long long)c << 32) | ((unsigned long long)d << 48);
}

// ---------------- K0: repack W0,W1 -> bf16 hi/lo, transposed to [n][k] --------------
__global__ __launch_bounds__(256) void repack_kernel(
    const float* __restrict__ W0, const float* __restrict__ W1,
    ushort* __restrict__ Wth, ushort* __restrict__ Wtl)
{
    int g = blockIdx.x * 256 + threadIdx.x;   // 0 .. 2*65536-1
    int mat = g >> 16;
    int idx = g & 65535;
    int c = idx >> 8, k = idx & 255;
    const float* W = mat ? W1 : W0;
    float v = W[(c >> 6) * (256 * 64) + k * 64 + (c & 63)];
    ushort h = f2bf(v);
    __builtin_nontemporal_store(h, &Wth[g]);                     // no dirty-L2 buildup
    __builtin_nontemporal_store(f2bf(v - bf2f(h)), &Wtl[g]);
}

// ---------------- K1: h0 = x @ Wc0 (split-bf16 MFMA) + layer-1 scores --------------
// A fp32 staged+converted once per block into LDS hi/lo; 500 blocks x 32 rows.
__global__ __launch_bounds__(256) void gemm1_kernel(
    const float* __restrict__ Af,
    const ushort* __restrict__ Bh, const ushort* __restrict__ Bl,
    const float* __restrict__ avec,
    float* __restrict__ out, float* __restrict__ s_t, float* __restrict__ s_n)
{
    __shared__ ushort sah[32 * LDP];
    __shared__ ushort sal[32 * LDP];
    const int wave = threadIdx.x >> 6, lane = threadIdx.x & 63;
    const int quad = lane >> 4, l16 = lane & 15;
    const int row0 = blockIdx.x * 32;            // 500*32 = 16000 exactly, no clamp
    const int col0 = wave * 64;

    for (int idx = threadIdx.x; idx < 32 * 64; idx += 256) {
        int row = idx >> 6, c4 = idx & 63;
        float4 f = ((const float4*)Af)[(size_t)(row0 + row) * 64 + c4];
        ushort4 h, l;
        h.x = f2bf(f.x); l.x = f2bf(f.x - bf2f(h.x));
        h.y = f2bf(f.y); l.y = f2bf(f.y - bf2f(h.y));
        h.z = f2bf(f.z); l.z = f2bf(f.z - bf2f(h.z));
        h.w = f2bf(f.w); l.w = f2bf(f.w - bf2f(h.w));
        *(ushort4*)(&sah[row * LDP + c4 * 4]) = h;
        *(ushort4*)(&sal[row * LDP + c4 * 4]) = l;
    }
    __syncthreads();

    f32x4 acc[2][4];
#pragma unroll
    for (int r = 0; r < 2; ++r)
#pragma unroll
        for (int c = 0; c < 4; ++c) acc[r][c] = (f32x4){0.f, 0.f, 0.f, 0.f};
    const int kbase = quad * 8;

    for (int k0 = 0; k0 < 256; k0 += 32) {
        bf16x8 a_h[2], a_l[2], b_h[4], b_l[4];
#pragma unroll
        for (int r = 0; r < 2; ++r) {
            int loff = (r * 16 + l16) * LDP + k0 + kbase;
            a_h[r] = *(const bf16x8*)(&sah[loff]);
            a_l[r] = *(const bf16x8*)(&sal[loff]);
        }
#pragma unroll
        for (int c = 0; c < 4; ++c) {
            int off = (col0 + c * 16 + l16) * 256 + k0 + kbase;
            b_h[c] = *(const bf16x8*)(Bh + off);
            b_l[c] = *(const bf16x8*)(Bl + off);
        }
#pragma unroll
        for (int r = 0; r < 2; ++r)
#pragma unroll
            for (int c = 0; c < 4; ++c) {
                acc[r][c] = __builtin_amdgcn_mfma_f32_16x16x32_bf16(a_h[r], b_h[c], acc[r][c], 0, 0, 0);
                acc[r][c] = __builtin_amdgcn_mfma_f32_16x16x32_bf16(a_h[r], b_l[c], acc[r][c], 0, 0, 0);
                acc[r][c] = __builtin_amdgcn_mfma_f32_16x16x32_bf16(a_l[r], b_h[c], acc[r][c], 0, 0, 0);
            }
    }

    // C/D layout: col = lane&15, row = quad*4 + reg  [measured m89/m91]
#pragma unroll
    for (int r = 0; r < 2; ++r)
#pragma unroll
        for (int c = 0; c < 4; ++c) {
            int col = col0 + c * 16 + l16;
#pragma unroll
            for (int reg = 0; reg < 4; ++reg) {
                int row = row0 + r * 16 + quad * 4 + reg;
                __builtin_nontemporal_store(acc[r][c][reg], &out[(size_t)row * 256 + col]);
            }
        }

    // fused layer-1 scores: head == wave
    float at[4], an[4];
#pragma unroll
    for (int c = 0; c < 4; ++c) {
        at[c] = avec[wave * 128 + c * 16 + l16];
        an[c] = avec[wave * 128 + 64 + c * 16 + l16];
    }
#pragma unroll
    for (int r = 0; r < 2; ++r) {
        float pt[4] = {0.f, 0.f, 0.f, 0.f}, pn[4] = {0.f, 0.f, 0.f, 0.f};
#pragma unroll
        for (int c = 0; c < 4; ++c)
#pragma unroll
            for (int reg = 0; reg < 4; ++reg) {
                pt[reg] += acc[r][c][reg] * at[c];
                pn[reg] += acc[r][c][reg] * an[c];
            }
#pragma unroll
        for (int reg = 0; reg < 4; ++reg)
#pragma unroll
            for (int m = 1; m < 16; m <<= 1) {
                pt[reg] += __shfl_xor(pt[reg], m);
                pn[reg] += __shfl_xor(pn[reg], m);
            }
        if (l16 == 0) {
#pragma unroll
            for (int reg = 0; reg < 4; ++reg) {
                int row = row0 + r * 16 + quad * 4 + reg;
                __builtin_nontemporal_store(pt[reg], &s_t[wave * N2C + row]);
                __builtin_nontemporal_store(pn[reg], &s_n[wave * N2C + row]);
            }
        }
    }
}

// ---------------- K2: att1 — one target/block (4000 blocks, high TLP for gather) ----
__global__ __launch_bounds__(256) void att_kernel(
    const float* __restrict__ hprev, const int* __restrict__ nbr_arr,
    const float* __restrict__ s_t, const float* __restrict__ s_n,
    ushort* __restrict__ outhi, ushort* __restrict__ outlo, int T, int Nsrc)
{
    __shared__ int nbr[DEG + 1];
    __shared__ float att_s[NHEAD][DEG + 3];
    __shared__ float4 red[4][64];
    const int tgt = blockIdx.x;
    const int t = threadIdx.x;
    const int lane = t & 63;
    if (t < DEG) nbr[t] = nbr_arr[tgt * DEG + t];
    else if (t == DEG) nbr[DEG] = nbr_arr[T * DEG + tgt];  // self-loop edge
    __syncthreads();

    {   // wave = head; lane = edge index (33 edges), lanes 33..63 inert
        const int hd = t >> 6;
        int me = (lane <= DEG) ? nbr[lane] : -1;
        int k = (lane <= DEG) ? 1 : 0;
#pragma unroll
        for (int j = 0; j < DEG; ++j) {          // dedupe scan via shuffle
            int v = __shfl(me, j);
            if (j < lane && v == me) k = 0;
        }
        float e = s_t[hd * Nsrc + tgt] + ((lane <= DEG) ? s_n[hd * Nsrc + me] : 0.f);
        e = (e >= 0.f) ? e : ALPHA * e;          // LeakyReLU(0.2)
        float em = k ? e : -1e30f;
        float m = em;
#pragma unroll
        for (int off = 1; off < 64; off <<= 1) m = fmaxf(m, __shfl_xor(m, off));
        float w = k ? __expf(e - m) : 0.f;
        float Z = w;
#pragma unroll
        for (int off = 1; off < 64; off <<= 1) Z += __shfl_xor(Z, off);
        if (lane <= DEG) att_s[hd][lane] = w / Z;
    }
    __syncthreads();

    // aggregation: thread = (rg = t>>6 row-group, cq = t&63 channel-quad)
    const int cq = t & 63;
    const int rg = t >> 6;
    const int hd = cq >> 4;
    const float4* hp4 = (const float4*)hprev;
    float4 acc = make_float4(0.f, 0.f, 0.f, 0.f);
#pragma unroll
    for (int ii = 0; ii < 9; ++ii) {
        int i = rg + ii * 4;
        if (i <= DEG) {
            float w = att_s[hd][i];                       // dup edges: w==0
            float4 v = hp4[(size_t)nbr[i] * 64 + cq];
            acc.x += w * v.x; acc.y += w * v.y;
            acc.z += w * v.z; acc.w += w * v.w;
        }
    }
    red[rg][cq] = acc;
    __syncthreads();
    if (t < 64) {
        float4 s0 = red[0][t], s1 = red[1][t], s2 = red[2][t], s3 = red[3][t];
        float4 s;
        s.x = s0.x + s1.x + s2.x + s3.x;
        s.y = s0.y + s1.y + s2.y + s3.y;
        s.z = s0.z + s1.z + s2.z + s3.z;
        s.w = s0.w + s1.w + s2.w + s3.w;
        s.x = (s.x > 0.f) ? s.x : expm1f(s.x);   // ELU
        s.y = (s.y > 0.f) ? s.y : expm1f(s.y);
        s.z = (s.z > 0.f) ? s.z : expm1f(s.z);
        s.w = (s.w > 0.f) ? s.w : expm1f(s.w);
        ushort hx = f2bf(s.x), hy = f2bf(s.y), hz = f2bf(s.z), hw = f2bf(s.w);
        ushort lx = f2bf(s.x - bf2f(hx)), ly = f2bf(s.y - bf2f(hy));
        ushort lz = f2bf(s.z - bf2f(hz)), lw = f2bf(s.w - bf2f(hw));
        __builtin_nontemporal_store(pack4(hx, hy, hz, hw),
            &((unsigned long long*)outhi)[tgt * 64 + t]);
        __builtin_nontemporal_store(pack4(lx, ly, lz, lw),
            &((unsigned long long*)outlo)[tgt * 64 + t]);
    }
}

// ---------------- K3: gemm2 = x1 @ Wc1 (A bf16 hi/lo from global) + layer-2 scores --
// 250 blocks x 16 rows.
__global__ __launch_bounds__(256) void gemm2_kernel(
    const ushort* __restrict__ Ah, const ushort* __restrict__ Al,
    const ushort* __restrict__ Bh, const ushort* __restrict__ Bl,
    const float* __restrict__ avec,
    float* __restrict__ h1, float* __restrict__ st2, float* __restrict__ sn2)
{
    const int wave = threadIdx.x >> 6, lane = threadIdx.x & 63;
    const int quad = lane >> 4, l16 = lane & 15;
    const int row0 = blockIdx.x * 16;            // 250*16 = 4000 exactly
    const int col0 = wave * 64;
    const int kbase = quad * 8;
    const int arow = row0 + l16;

    f32x4 acc2[4];
#pragma unroll
    for (int c = 0; c < 4; ++c) acc2[c] = (f32x4){0.f, 0.f, 0.f, 0.f};

    for (int k0 = 0; k0 < 256; k0 += 32) {
        bf16x8 a_h, a_l, b_h[4], b_l[4];
        int aoff = arow * 256 + k0 + kbase;
        a_h = *(const bf16x8*)(Ah + aoff);
        a_l = *(const bf16x8*)(Al + aoff);
#pragma unroll
        for (int c = 0; c < 4; ++c) {
            int off = (col0 + c * 16 + l16) * 256 + k0 + kbase;
            b_h[c] = *(const bf16x8*)(Bh + off);
            b_l[c] = *(const bf16x8*)(Bl + off);
        }
#pragma unroll
        for (int c = 0; c < 4; ++c) {
            acc2[c] = __builtin_amdgcn_mfma_f32_16x16x32_bf16(a_h, b_h[c], acc2[c], 0, 0, 0);
            acc2[c] = __builtin_amdgcn_mfma_f32_16x16x32_bf16(a_h, b_l[c], acc2[c], 0, 0, 0);
            acc2[c] = __builtin_amdgcn_mfma_f32_16x16x32_bf16(a_l, b_h[c], acc2[c], 0, 0, 0);
        }
    }
#pragma unroll
    for (int c = 0; c < 4; ++c) {
        int col = col0 + c * 16 + l16;
#pragma unroll
        for (int reg = 0; reg < 4; ++reg) {
            int row = row0 + quad * 4 + reg;
            __builtin_nontemporal_store(acc2[c][reg], &h1[(size_t)row * 256 + col]);
        }
    }

    // fused layer-2 scores (head == wave)
    float at[4], an[4];
#pragma unroll
    for (int c = 0; c < 4; ++c) {
        at[c] = avec[wave * 128 + c * 16 + l16];
        an[c] = avec[wave * 128 + 64 + c * 16 + l16];
    }
    float pt[4] = {0.f, 0.f, 0.f, 0.f}, pn[4] = {0.f, 0.f, 0.f, 0.f};
#pragma unroll
    for (int c = 0; c < 4; ++c)
#pragma unroll
        for (int reg = 0; reg < 4; ++reg) {
            pt[reg] += acc2[c][reg] * at[c];
            pn[reg] += acc2[c][reg] * an[c];
        }
#pragma unroll
    for (int reg = 0; reg < 4; ++reg)
#pragma unroll
        for (int m = 1; m < 16; m <<= 1) {
            pt[reg] += __shfl_xor(pt[reg], m);
            pn[reg] += __shfl_xor(pn[reg], m);
        }
    if (l16 == 0) {
#pragma unroll
        for (int reg = 0; reg < 4; ++reg) {
            int row = row0 + quad * 4 + reg;
            __builtin_nontemporal_store(pt[reg], &st2[wave * N1C + row]);
            __builtin_nontemporal_store(pn[reg], &sn2[wave * N1C + row]);
        }
    }
}

// ---------------- K4: att2 + final Linear + Tanh (4 targets/block, wave = target) ---
__global__ __launch_bounds__(256) void att_lin_kernel(
    const float* __restrict__ h1, const int* __restrict__ nbr_arr,
    const float* __restrict__ s_t, const float* __restrict__ s_n,
    const float* __restrict__ linW, const float* __restrict__ bias,
    float* __restrict__ out)
{
    __shared__ int   nbr_s[4][DEG + 1];
    __shared__ float att_w[4][NHEAD][DEG + 1];
    __shared__ float x2[4][256];

    const int wave = threadIdx.x >> 6, lane = threadIdx.x & 63;
    const int blk = blockIdx.x;                  // 250 blocks * 4 targets = 1000

    for (int idx = threadIdx.x; idx < 4 * (DEG + 1); idx += 256) {
        int tt = idx / (DEG + 1), e = idx - tt * (DEG + 1);
        nbr_s[tt][e] = (e < DEG) ? nbr_arr[(blk * 4 + tt) * DEG + e]
                                 : nbr_arr[N0C * DEG + blk * 4 + tt];
    }
    __syncthreads();

    {
        const int tl = wave;
        const int gt = blk * 4 + tl;
        int me = (lane <= DEG) ? nbr_s[tl][lane] : 0;
        int k = (lane <= DEG) ? 1 : 0;
#pragma unroll
        for (int j = 0; j < DEG; ++j) {
            int v = __shfl(me, j);
            if (j < lane && v == me) k = 0;
        }
#pragma unroll
        for (int hd = 0; hd < NHEAD; ++hd) {
            float e = s_t[hd * N1C + gt] + s_n[hd * N1C + me];
            e = (e >= 0.f) ? e : ALPHA * e;
            float em = k ? e : -1e30f;
            float m = em;
#pragma unroll
            for (int off = 1; off < 64; off <<= 1) m = fmaxf(m, __shfl_xor(m, off));
            float w = k ? __expf(e - m) : 0.f;
            float Z = w;
#pragma unroll
            for (int off = 1; off < 64; off <<= 1) Z += __shfl_xor(Z, off);
            if (lane <= DEG) att_w[tl][hd][lane] = w / Z;
        }
    }
    __syncthreads();
    {
        const int tl = wave;
        const int hh = lane >> 4;
        float4 acc = make_float4(0.f, 0.f, 0.f, 0.f);
#pragma unroll
        for (int e = 0; e <= DEG; ++e) {
            float w = att_w[tl][hh][e];
            float4 v = ((const float4*)h1)[(size_t)nbr_s[tl][e] * 64 + lane];
            acc.x += w * v.x; acc.y += w * v.y;
            acc.z += w * v.z; acc.w += w * v.w;
        }
        acc.x = (acc.x > 0.f) ? acc.x : expm1f(acc.x);   // ELU
        acc.y = (acc.y > 0.f) ? acc.y : expm1f(acc.y);
        acc.z = (acc.z > 0.f) ? acc.z : expm1f(acc.z);
        acc.w = (acc.w > 0.f) ? acc.w : expm1f(acc.w);
        *(float4*)(&x2[tl][lane * 4]) = acc;
    }
    __syncthreads();

    // final linear: thread = output channel c; fp32 matvec over linW row [c][0..255]
    const int c = threadIdx.x;
    const float4* wrow = (const float4*)(linW + c * 256);
    float v0 = 0.f, v1 = 0.f, v2 = 0.f, v3 = 0.f;
    for (int q = 0; q < 64; ++q) {
        float4 wv = wrow[q];
        int kk = q * 4;
        v0 += x2[0][kk] * wv.x + x2[0][kk+1] * wv.y + x2[0][kk+2] * wv.z + x2[0][kk+3] * wv.w;
        v1 += x2[1][kk] * wv.x + x2[1][kk+1] * wv.y + x2[1][kk+2] * wv.z + x2[1][kk+3] * wv.w;
        v2 += x2[2][kk] * wv.x + x2[2][kk+1] * wv.y + x2[2][kk+2] * wv.z + x2[2][kk+3] * wv.w;
        v3 += x2[3][kk] * wv.x + x2[3][kk+1] * wv.y + x2[3][kk+2] * wv.z + x2[3][kk+3] * wv.w;
    }
    float b = bias[c];
    out[(size_t)(blk * 4 + 0) * 256 + c] = tanhf(v0 + b);
    out[(size_t)(blk * 4 + 1) * 256 + c] = tanhf(v1 + b);
    out[(size_t)(blk * 4 + 2) * 256 + c] = tanhf(v2 + b);
    out[(size_t)(blk * 4 + 3) * 256 + c] = tanhf(v3 + b);
}

extern "C" void kernel_launch(void* const* d_in, const int* in_sizes, int n_in,
                              void* d_out, int out_size, void* d_ws, size_t ws_size,
                              hipStream_t stream)
{
    const float* x    = (const float*)d_in[0];
    const float* W0   = (const float*)d_in[1];
    const float* a0   = (const float*)d_in[2];
    const float* W1   = (const float*)d_in[3];
    const float* a1   = (const float*)d_in[4];
    const float* linW = (const float*)d_in[5];
    const float* linb = (const float*)d_in[6];
    const int* adj1_nbr = (const int*)d_in[8];
    const int* adj0_nbr = (const int*)d_in[10];

    char* base = (char*)d_ws;
    ushort* Wth = (ushort*)base;                 // 2*65536 ushort = 256 KB
    ushort* Wtl = (ushort*)(base + 262144);      // 256 KB          (ends 524288)
    float*  st  = (float*)(base + 524288);       // 4*16000 f32 (256 KB slot)
    float*  sn  = (float*)(base + 786432);       //                 (ends 1048576)
    float*  st2 = (float*)(base + 1048576);      // 4*4000 f32 (64 KB slot)
    float*  sn2 = (float*)(base + 1114112);      //                 (ends 1179648)
    ushort* xhi = (ushort*)(base + 1179648);     // 4000*256 u16 = 2 MB
    ushort* xlo = (ushort*)(base + 3276800);     // 2 MB            (ends 5373952)
    float*  h0  = (float*)(base + 5373952);      // 16000*256 f32 = 16 MB
    float*  h1  = (float*)(base + 21757952);     // 4000*256 f32 = 4 MB (ends ~25.8 MB)

    // K0: weight repack (W0,W1 -> bf16 hi/lo, [n][k]); linW stays fp32
    repack_kernel<<<512, 256, 0, stream>>>(W0, W1, Wth, Wtl);

    // K1: h0 = x @ Wc0 + layer-1 scores
    gemm1_kernel<<<N2C / 32, 256, 0, stream>>>(x, Wth, Wtl, a0, h0, st, sn);

    // K2: att1 (4000 blocks — TLP hides gather latency; round-4 lesson)
    att_kernel<<<N1C, 256, 0, stream>>>(h0, adj1_nbr, st, sn, xhi, xlo, N1C, N2C);

    // K3: gemm2 = x1 @ Wc1 + layer-2 scores
    gemm2_kernel<<<N1C / 16, 256, 0, stream>>>(
        xhi, xlo, Wth + 65536, Wtl + 65536, a1, h1, st2, sn2);

    // K4: att2 -> Linear+Tanh, fused
    att_lin_kernel<<<N0C / 4, 256, 0, stream>>>(
        h1, adj0_nbr, st2, sn2, linW, linb, (float*)d_out);
}